// Round 1
// baseline (490.911 us; speedup 1.0000x reference)
//
#include <hip/hip_runtime.h>
#include <hip/hip_bf16.h>
#include <cstdint>
#include <cstddef>

#define B_ 8
#define T_ 4096
#define D_ 1024
#define H_ 1024
#define M_ (B_*T_)
#define NCHUNK 64
#define CLEN 64

using bf16x8   = __attribute__((ext_vector_type(8))) __bf16;
using floatx4  = __attribute__((ext_vector_type(4))) float;
using float4v  = __attribute__((ext_vector_type(4))) float;
using ushort4v = __attribute__((ext_vector_type(4))) unsigned short;
using aw2_t    = __attribute__((ext_vector_type(2))) _Float16;  // packed (a, w)
using halfx8   = __attribute__((ext_vector_type(8))) _Float16;  // 4 aw2 pairs

__device__ inline unsigned short f2bf(float f) {
  union { float f; unsigned u; } v; v.f = f;
  unsigned u = v.u;
  u += 0x7fffu + ((u >> 16) & 1u);   // round-to-nearest-even
  return (unsigned short)(u >> 16);
}

__device__ inline void async_load16(const void* g, void* l) {
  __builtin_amdgcn_global_load_lds((const __attribute__((address_space(1))) void*)g,
                                   (__attribute__((address_space(3))) void*)l,
                                   16, 0, 0);
}

// ---------------- cast x (fp32 -> bf16), 8 elems/thread ----------------
__global__ __launch_bounds__(256) void cast_x_kernel(const float* __restrict__ x,
                                                     unsigned short* __restrict__ xb) {
  size_t i = ((size_t)blockIdx.x * 256 + threadIdx.x) * 2;  // 2 groups of 4
#pragma unroll
  for (int j = 0; j < 2; ++j) {
    float4v v = ((const float4v*)x)[i + j];
    ushort4v o = { f2bf(v[0]), f2bf(v[1]), f2bf(v[2]), f2bf(v[3]) };
    ((ushort4v*)xb)[i + j] = o;
  }
}

// ------------- transpose + cast W [K][N] -> Wt [N][K] bf16 -------------
__global__ __launch_bounds__(256) void transpose_w_kernel(const float* __restrict__ Wz,
                                                          const float* __restrict__ Wh,
                                                          unsigned short* __restrict__ Wzt,
                                                          unsigned short* __restrict__ Wht) {
  __shared__ float tile[32][33];
  const float* W = blockIdx.z ? Wh : Wz;
  unsigned short* Wt = blockIdx.z ? Wht : Wzt;
  int n0 = blockIdx.x * 32, k0 = blockIdx.y * 32;
#pragma unroll
  for (int j = 0; j < 4; ++j) {
    int kr = threadIdx.y + j * 8;
    tile[kr][threadIdx.x] = W[(size_t)(k0 + kr) * H_ + n0 + threadIdx.x];
  }
  __syncthreads();
#pragma unroll
  for (int j = 0; j < 4; ++j) {
    int nr = threadIdx.y + j * 8;
    Wt[(size_t)(n0 + nr) * D_ + k0 + threadIdx.x] = f2bf(tile[threadIdx.x][nr]);
  }
}

// ------------- dual-output MFMA GEMM, 8-phase counted-vmcnt schedule -------------
// BM=256 x BN=128 dual tile, BK=64 as 2 K-halves of 32. 8 waves (4m x 2n),
// per-wave 64x64 dual output. LDS = 4-slot ring of K-half buffers
// {A 16KB + Bz 8KB + Bh 8KB} = 128KB (1 block/CU, 8 waves/CU).
// Per K-tile: 4 phases {ds_read subtile + issue 2 global_load_lds -> s_barrier
// -> lgkmcnt(0) -> setprio(1) -> 16 MFMA -> setprio(0) -> s_barrier}.
// Counted s_waitcnt vmcnt(4) twice per K-tile (never 0 in main loop):
// staging runs 2 K-halves ahead of compute in the 4-slot ring.
// LDS swizzle: half-buffer row r (64B = 4x16B blocks), logical k-block j
// stored at slot (j + (r>>1))&3 -> frag ds_read_b128 is 2-way (free).
// global_load_lds dest stays linear (seg*16B); source absorbs the swizzle:
// j = ((tid&3) - ((tid>>3)&3)) & 3, t-independent (rows step 128 == 0 mod 4).
__global__ __launch_bounds__(512, 2) void gemm_kernel(
    const unsigned short* __restrict__ xb,    // [M_][D_] bf16
    const unsigned short* __restrict__ wzt,   // [H_][D_] bf16 (transposed)
    const unsigned short* __restrict__ wht,   // [H_][D_] bf16
    const float* __restrict__ bz, const float* __restrict__ bh,
    aw2_t* __restrict__ aw_out) {
  __shared__ __align__(16) unsigned short ldsA[4][8192];   // 4 x 256 rows x 32 k
  __shared__ __align__(16) unsigned short ldsBz[4][4096];  // 4 x 128 rows x 32 k
  __shared__ __align__(16) unsigned short ldsBh[4][4096];

  const int tid = threadIdx.x;               // 0..511
  const int lane = tid & 63, wid = tid >> 6; // 8 waves
  const int wm = wid >> 1, wn = wid & 1;     // 4m x 2n wave grid
  const int row16 = lane & 15, quad = lane >> 4;

  // XCD-aware swizzle: 1024 blocks, 8 XCDs; each XCD owns 16 contiguous
  // m-strips, iterating 8 n-tiles per strip (A panel L2-resident).
  int g = blockIdx.x;
  int x = g & 7, j = g >> 3;                 // j in 0..127
  int n_idx = j & 7;
  int m_idx = (x << 4) | (j >> 3);
  const int m0 = m_idx << 8, n0 = n_idx << 7;

  floatx4 accz[4][4], acch[4][4];
#pragma unroll
  for (int mi = 0; mi < 4; ++mi)
#pragma unroll
    for (int ni = 0; ni < 4; ++ni) {
      accz[mi][ni] = (floatx4){0.f, 0.f, 0.f, 0.f};
      acch[mi][ni] = (floatx4){0.f, 0.f, 0.f, 0.f};
    }

  // staging: seg s = tid + 512*t: row = s>>2, slot p = s&3,
  // logical k-block j = (p - (row>>1))&3 = ((tid&3) - ((tid>>3)&3))&3.
  const int srow = tid >> 2;                 // 0..127
  const int jA = ((tid & 3) - ((tid >> 3) & 3)) & 3;
  const unsigned short* aS0 = xb  + (size_t)(m0 + srow) * D_ + jA * 8;
  const unsigned short* aS1 = aS0 + (size_t)128 * D_;
  const unsigned short* zS  = wzt + (size_t)(n0 + srow) * D_ + jA * 8;
  const unsigned short* hS  = wht + (size_t)(n0 + srow) * D_ + jA * 8;

  // frag reads: row r, k-block quad -> slot (quad + (r>>1))&3;
  // (r>>1)&3 reduces to (row16>>1)&3 (mi*16, wm*64 are 0 mod 8).
  const int sl = (quad + (row16 >> 1)) & 3;
  const int aoff = (wm * 64 + row16) * 32 + sl * 8;   // + mi*512
  const int boff = (wn * 64 + row16) * 32 + sl * 8;   // + ni*512

  // ---- prologue: stage halves 0 and 1 of K-tile 0 ----
  async_load16(aS0 +  0, &ldsA[0][tid * 8]);
  async_load16(aS1 +  0, &ldsA[0][tid * 8 + 4096]);
  async_load16(zS  +  0, &ldsBz[0][tid * 8]);
  async_load16(hS  +  0, &ldsBh[0][tid * 8]);
  async_load16(aS0 + 32, &ldsA[1][tid * 8]);
  async_load16(aS1 + 32, &ldsA[1][tid * 8 + 4096]);
  async_load16(zS  + 32, &ldsBz[1][tid * 8]);
  async_load16(hS  + 32, &ldsBh[1][tid * 8]);
  asm volatile("s_waitcnt vmcnt(4)" ::: "memory");   // half 0 resident
  __builtin_amdgcn_s_barrier();

#define MFMA16(ACC, BF)                                                          \
  __builtin_amdgcn_s_setprio(1);                                                 \
  _Pragma("unroll")                                                              \
  for (int mi = 0; mi < 4; ++mi)                                                 \
    _Pragma("unroll")                                                            \
    for (int ni = 0; ni < 4; ++ni)                                               \
      ACC[mi][ni] = __builtin_amdgcn_mfma_f32_16x16x32_bf16(af[mi], BF[ni],      \
                                                            ACC[mi][ni], 0, 0, 0); \
  __builtin_amdgcn_s_setprio(0);

#pragma unroll 1
  for (int kt = 0; kt < 16; ++kt) {
    const int s0 = (2 * kt) & 3, s1 = s0 + 1;        // compute slots (s0 in {0,2})
    const int t0 = (s0 + 2) & 3, t1 = (s0 + 3) & 3;  // stage slots (tile kt+1)
    const int kN = ((kt + 1) & 15) * 64;             // next-tile k base
    const bool st = (kt < 15);
    bf16x8 af[4], bzf[4], bhf[4];

    // ---- P0: read A,Bz of half s0; stage A of half (2kt+2); MFMA accz kh0 ----
#pragma unroll
    for (int mi = 0; mi < 4; ++mi)
      af[mi] = *(const bf16x8*)&ldsA[s0][aoff + mi * 512];
#pragma unroll
    for (int ni = 0; ni < 4; ++ni)
      bzf[ni] = *(const bf16x8*)&ldsBz[s0][boff + ni * 512];
    if (st) {
      async_load16(aS0 + kN, &ldsA[t0][tid * 8]);
      async_load16(aS1 + kN, &ldsA[t0][tid * 8 + 4096]);
    }
    __builtin_amdgcn_s_barrier();
    asm volatile("s_waitcnt lgkmcnt(0)" ::: "memory");
    MFMA16(accz, bzf)
    __builtin_amdgcn_s_barrier();

    // ---- P1: read Bh of half s0; stage Bz,Bh of half (2kt+2); MFMA acch kh0 ----
#pragma unroll
    for (int ni = 0; ni < 4; ++ni)
      bhf[ni] = *(const bf16x8*)&ldsBh[s0][boff + ni * 512];
    if (st) {
      async_load16(zS + kN, &ldsBz[t0][tid * 8]);
      async_load16(hS + kN, &ldsBh[t0][tid * 8]);
      asm volatile("s_waitcnt vmcnt(4)" ::: "memory");  // half s1 resident; t0's 4 fly
    } else {
      asm volatile("s_waitcnt vmcnt(0)" ::: "memory");  // last tile: drain half 31
    }
    __builtin_amdgcn_s_barrier();
    asm volatile("s_waitcnt lgkmcnt(0)" ::: "memory");
    MFMA16(acch, bhf)
    __builtin_amdgcn_s_barrier();

    // ---- P2: read A,Bz of half s1; stage A of half (2kt+3); MFMA accz kh1 ----
#pragma unroll
    for (int mi = 0; mi < 4; ++mi)
      af[mi] = *(const bf16x8*)&ldsA[s1][aoff + mi * 512];
#pragma unroll
    for (int ni = 0; ni < 4; ++ni)
      bzf[ni] = *(const bf16x8*)&ldsBz[s1][boff + ni * 512];
    if (st) {
      async_load16(aS0 + kN + 32, &ldsA[t1][tid * 8]);
      async_load16(aS1 + kN + 32, &ldsA[t1][tid * 8 + 4096]);
    }
    __builtin_amdgcn_s_barrier();
    asm volatile("s_waitcnt lgkmcnt(0)" ::: "memory");
    MFMA16(accz, bzf)
    __builtin_amdgcn_s_barrier();

    // ---- P3: read Bh of half s1; stage Bz,Bh of half (2kt+3); MFMA acch kh1 ----
#pragma unroll
    for (int ni = 0; ni < 4; ++ni)
      bhf[ni] = *(const bf16x8*)&ldsBh[s1][boff + ni * 512];
    if (st) {
      async_load16(zS + kN + 32, &ldsBz[t1][tid * 8]);
      async_load16(hS + kN + 32, &ldsBh[t1][tid * 8]);
      asm volatile("s_waitcnt vmcnt(4)" ::: "memory");  // half t0 resident; t1's 4 fly
    }
    __builtin_amdgcn_s_barrier();
    asm volatile("s_waitcnt lgkmcnt(0)" ::: "memory");
    MFMA16(acch, bhf)
    __builtin_amdgcn_s_barrier();
  }
#undef MFMA16

  // epilogue: C/D layout col=lane&15, row=quad*4+reg
#pragma unroll
  for (int mi = 0; mi < 4; ++mi) {
#pragma unroll
    for (int ni = 0; ni < 4; ++ni) {
      int col = n0 + wn * 64 + ni * 16 + row16;
      float bzv = bz[col], bhv = bh[col];
#pragma unroll
      for (int r = 0; r < 4; ++r) {
        int row = m0 + wm * 64 + mi * 16 + quad * 4 + r;
        float k   = accz[mi][ni][r] + bzv;
        float pre = acch[mi][ni][r] + bhv;
        float z  = 1.f / (1.f + __expf(-k));   // sigmoid(k)
        float av = 1.f / (1.f + __expf(k));    // sigmoid(-k) = 1-z
        float gg = (pre >= 0.f) ? (pre + 0.5f) : 1.f / (1.f + __expf(-pre));
        aw2_t o = { (_Float16)av, (_Float16)(z * gg) };
        aw_out[(size_t)row * H_ + col] = o;
      }
    }
  }
}

// ------------- scan pass 1: per-chunk (P = prod a, S = local scan), 4 h per thread -------------
// P,S layout: [b][h][c]  (contiguous in c for fast pass2)
__global__ __launch_bounds__(256) void scan_pass1(const halfx8* __restrict__ aw,
                                                  float* __restrict__ P, float* __restrict__ S) {
  int c = blockIdx.x;     // chunk
  int b = blockIdx.y;     // batch
  int h4 = threadIdx.x;   // h = h4*4
  size_t base = (size_t)(b * T_ + c * CLEN) * (H_ / 4) + h4;
  float p0 = 1.f, p1 = 1.f, p2 = 1.f, p3 = 1.f;
  float s0 = 0.f, s1 = 0.f, s2 = 0.f, s3 = 0.f;
#pragma unroll 8
  for (int i = 0; i < CLEN; ++i) {
    halfx8 v = aw[base + (size_t)i * (H_ / 4)];
    float a0 = (float)v[0], w0 = (float)v[1];
    float a1 = (float)v[2], w1 = (float)v[3];
    float a2 = (float)v[4], w2 = (float)v[5];
    float a3 = (float)v[6], w3 = (float)v[7];
    s0 = a0 * s0 + w0; p0 *= a0;
    s1 = a1 * s1 + w1; p1 *= a1;
    s2 = a2 * s2 + w2; p2 *= a2;
    s3 = a3 * s3 + w3; p3 *= a3;
  }
  size_t o = ((size_t)b * H_ + h4 * 4) * NCHUNK + c;
  P[o] = p0; P[o + NCHUNK] = p1; P[o + 2 * NCHUNK] = p2; P[o + 3 * NCHUNK] = p3;
  S[o] = s0; S[o + NCHUNK] = s1; S[o + 2 * NCHUNK] = s2; S[o + 3 * NCHUNK] = s3;
}

// ------------- scan pass 2: chunk-level carries + out[:,0,:] -------------
__global__ __launch_bounds__(256) void scan_pass2(const float* __restrict__ h0,
                                                  const float* __restrict__ P,
                                                  const float* __restrict__ S,
                                                  float* __restrict__ carry,
                                                  float* __restrict__ out) {
  int gid = blockIdx.x * 256 + threadIdx.x;  // 0..8191
  int b = gid >> 10, h = gid & 1023;
  float v = h0[(size_t)b * H_ + h];
  float cur = (v >= 0.f) ? (v + 0.5f) : 1.f / (1.f + __expf(-v));  // g(h0)
  out[((size_t)b * (T_ + 1)) * H_ + h] = cur;
  const float4v* Pv = (const float4v*)&P[((size_t)b * H_ + h) * NCHUNK];
  const float4v* Sv = (const float4v*)&S[((size_t)b * H_ + h) * NCHUNK];
  float4v* Cv = (float4v*)&carry[((size_t)b * H_ + h) * NCHUNK];
#pragma unroll
  for (int j = 0; j < NCHUNK / 4; ++j) {
    float4v p = Pv[j], s = Sv[j], cc;
    cc[0] = cur; cur = p[0] * cur + s[0];
    cc[1] = cur; cur = p[1] * cur + s[1];
    cc[2] = cur; cur = p[2] * cur + s[2];
    cc[3] = cur; cur = p[3] * cur + s[3];
    Cv[j] = cc;
  }
}

// ------------- scan pass 3: replay chunks with carries, write out (4 h per thread) -------------
__global__ __launch_bounds__(256) void scan_pass3(const halfx8* __restrict__ aw,
                                                  const float* __restrict__ carry,
                                                  float* __restrict__ out) {
  int c = blockIdx.x;
  int b = blockIdx.y;
  int h4 = threadIdx.x;   // h = h4*4
  size_t base = (size_t)(b * T_ + c * CLEN) * (H_ / 4) + h4;
  size_t cb = ((size_t)b * H_ + h4 * 4) * NCHUNK + c;
  float c0 = carry[cb], c1 = carry[cb + NCHUNK], c2 = carry[cb + 2 * NCHUNK], c3 = carry[cb + 3 * NCHUNK];
  size_t obase = ((size_t)b * (T_ + 1) + c * CLEN + 1) * (H_ / 4) + h4;
  float4v* outv = (float4v*)out;
#pragma unroll 8
  for (int i = 0; i < CLEN; ++i) {
    halfx8 v = aw[base + (size_t)i * (H_ / 4)];
    c0 = (float)v[0] * c0 + (float)v[1];
    c1 = (float)v[2] * c1 + (float)v[3];
    c2 = (float)v[4] * c2 + (float)v[5];
    c3 = (float)v[6] * c3 + (float)v[7];
    float4v o = { c0, c1, c2, c3 };
    outv[obase + (size_t)i * (H_ / 4)] = o;
  }
}

extern "C" void kernel_launch(void* const* d_in, const int* in_sizes, int n_in,
                              void* d_out, int out_size, void* d_ws, size_t ws_size,
                              hipStream_t stream) {
  const float* x  = (const float*)d_in[0];
  const float* h0 = (const float*)d_in[1];
  const float* Wz = (const float*)d_in[2];
  const float* bz = (const float*)d_in[3];
  const float* Wh = (const float*)d_in[4];
  const float* bh = (const float*)d_in[5];
  float* out = (float*)d_out;

  char* ws = (char*)d_ws;
  // layout: xb 64MB | wzt 2MB | wht 2MB | aw 128MB | P 2MB | S 2MB | carry 2MB
  unsigned short* xb  = (unsigned short*)(ws);
  unsigned short* wzt = (unsigned short*)(ws + 67108864ULL);
  unsigned short* wht = (unsigned short*)(ws + 69206016ULL);
  aw2_t* aw_ws = (aw2_t*)(ws + 71303168ULL);
  float* P_ws  = (float*)(ws + 71303168ULL + 134217728ULL);
  float* S_ws  = (float*)(ws + 71303168ULL + 134217728ULL + 2097152ULL);
  float* c_ws  = (float*)(ws + 71303168ULL + 134217728ULL + 2ULL * 2097152ULL);

  hipLaunchKernelGGL(cast_x_kernel, dim3(16384), dim3(256), 0, stream, x, xb);
  hipLaunchKernelGGL(transpose_w_kernel, dim3(32, 32, 2), dim3(32, 8), 0, stream, Wz, Wh, wzt, wht);
  hipLaunchKernelGGL(gemm_kernel, dim3(1024), dim3(512), 0, stream,
                     xb, wzt, wht, bz, bh, aw_ws);
  hipLaunchKernelGGL(scan_pass1, dim3(NCHUNK, B_), dim3(256), 0, stream,
                     (const halfx8*)aw_ws, P_ws, S_ws);
  hipLaunchKernelGGL(scan_pass2, dim3(32), dim3(256), 0, stream, h0, P_ws, S_ws, c_ws, out);
  hipLaunchKernelGGL(scan_pass3, dim3(NCHUNK, B_), dim3(256), 0, stream,
                     (const halfx8*)aw_ws, c_ws, out);
}